// Round 3
// baseline (288.295 us; speedup 1.0000x reference)
//
#include <hip/hip_runtime.h>
#include <type_traits>

// SOC scan:  SOC[b,t] = SOC_init(b) + sum_{k<=t} g[k],  g[0]=0,
//   g[t]  = (ts[t]-ts[t-1]) * f[t-1]
//   f[t]  = coef * (1 + softplus(I*w1e0 + Te*w1e1 + b1e)*w2e + b2e) * I[t]
//   coef  = eta0 / (3600*Q)
//   SOC_init = S3 * (1 + softplus(I0*W1i0+Te0*W1i1+U0*W1i2+R*W1i3+b1i)*W2i + b2i)
//
// Round-2 post-mortem: tile-serial carry (128 barriers/block) was latency-bound
// (11% HBM). g[t] is LOCALLY computable -> one hierarchical block scan:
//   P1: 32 independent coalesced loads, g -> skewed LDS   (no barriers)
//   P2: per-thread serial scan of 32-elem LDS segment     (conflict-free skew)
//   P3: one 256-wide block scan of thread totals
//   P4: base + coalesced float4 stores
// Dtype self-detection kept (resolved f32 in round 2).

static __device__ __forceinline__ float bf2f(unsigned int u) {
    union { unsigned int i; float f; } v;
    v.i = u << 16;
    return v.f;
}
static __device__ __forceinline__ unsigned short f2bf(float f) {
    union { unsigned int i; float f; } v;
    v.f = f;
    unsigned int x = v.i;
    return (unsigned short)((x + 0x7fffu + ((x >> 16) & 1u)) >> 16);  // RNE
}
static __device__ __forceinline__ float softplus_f(float x) {
    return (x > 15.f) ? x : log1pf(expf(x));
}

struct F4 { float ts, I, Te, U; };
static __device__ __forceinline__ F4 dec(ushort4 x) {
    return {bf2f(x.x), bf2f(x.y), bf2f(x.z), bf2f(x.w)};
}
static __device__ __forceinline__ F4 dec(float4 x) {
    return {x.x, x.y, x.z, x.w};
}

template <bool BF16>
static __device__ __forceinline__ float ld(const void* p, int i) {
    return BF16 ? bf2f(((const unsigned short*)p)[i]) : ((const float*)p)[i];
}

constexpr int BLOCK = 256;
constexpr int MAXT  = 8192;
// skewed size: MAXT + MAXT/32
constexpr int GSZ = MAXT + MAXT / 32;

template <bool BF16>
static __device__ void run_scan(
    const void* __restrict__ Xv, const void* __restrict__ SCv,
    const void* __restrict__ W1i, const void* __restrict__ b1i,
    const void* __restrict__ W2i, const void* __restrict__ b2i,
    const void* __restrict__ W1e, const void* __restrict__ b1e,
    const void* __restrict__ W2e, const void* __restrict__ b2e,
    void* __restrict__ outv, int T)
{
    using XVec = typename std::conditional<BF16, ushort4, float4>::type;

    const int b    = blockIdx.x;
    const int tid  = threadIdx.x;
    const int lane = tid & 63;
    const int wave = tid >> 6;
    const int L    = T / BLOCK;   // segment length per thread (=32 at T=8192)

    __shared__ float s_g[GSZ];
    __shared__ float s_base[BLOCK];
    __shared__ float s_wtot[4];
    __shared__ float s_init;

    const float Q    = ld<BF16>(SCv, b * 4 + 0);
    const float eta0 = ld<BF16>(SCv, b * 4 + 1);
    const float R    = ld<BF16>(SCv, b * 4 + 2);
    const float S3   = ld<BF16>(SCv, b * 4 + 3);
    const float w1e0 = ld<BF16>(W1e, 0);
    const float w1e1 = ld<BF16>(W1e, 1);
    const float vb1e = ld<BF16>(b1e, 0);
    const float w2e  = ld<BF16>(W2e, 0);
    const float vb2e = ld<BF16>(b2e, 0);
    const float coef = eta0 / (3600.f * Q);

    const XVec* Xrow = (const XVec*)Xv + (size_t)b * T;

    // ---- Phase 1: independent chunk loads, compute g, skewed LDS store ----
    const int nchunk = T / BLOCK;
    #pragma unroll 4
    for (int c = 0; c < nchunk; ++c) {
        const int t = c * BLOCK + tid;
        const F4 v = dec(Xrow[t]);
        const float h = softplus_f(fmaf(v.I, w1e0, fmaf(v.Te, w1e1, vb1e)));
        const float f = coef * (1.f + fmaf(h, w2e, vb2e)) * v.I;
        float pts = __shfl_up(v.ts, 1, 64);
        float pf  = __shfl_up(f,  1, 64);
        if (lane == 0 && t > 0) {           // wave-boundary fixup, L1-hot reload
            const F4 vp = dec(Xrow[t - 1]);
            const float hp = softplus_f(fmaf(vp.I, w1e0, fmaf(vp.Te, w1e1, vb1e)));
            pf  = coef * (1.f + fmaf(hp, w2e, vb2e)) * vp.I;
            pts = vp.ts;
        }
        const float g = (t == 0) ? 0.f : (v.ts - pts) * pf;
        s_g[t + (t >> 5)] = g;
    }

    if (tid == 0) {                          // SOC_init head (X[b,0] L1-hot)
        const F4 v0 = dec(Xrow[0]);
        const float pre = fmaf(v0.I, ld<BF16>(W1i, 0),
                          fmaf(v0.Te, ld<BF16>(W1i, 1),
                          fmaf(v0.U, ld<BF16>(W1i, 2),
                          fmaf(R, ld<BF16>(W1i, 3), ld<BF16>(b1i, 0)))));
        const float h0 = softplus_f(pre);
        s_init = S3 * (1.f + fmaf(h0, ld<BF16>(W2i, 0), ld<BF16>(b2i, 0)));
    }
    __syncthreads();                         // B1: s_g + s_init complete

    // ---- Phase 2: per-thread serial inclusive scan of own segment ----
    float run = 0.f;
    for (int j = 0; j < L; ++j) {
        const int t = tid * L + j;
        const int a = t + (t >> 5);
        run += s_g[a];
        s_g[a] = run;                        // own addresses; no barrier needed
    }

    // ---- Phase 3: block scan of thread totals ----
    const float tot = run;
    float sc = tot;
    #pragma unroll
    for (int d = 1; d < 64; d <<= 1) {
        const float u = __shfl_up(sc, d, 64);
        if (lane >= d) sc += u;
    }
    if (lane == 63) s_wtot[wave] = sc;
    __syncthreads();                         // B2: wave totals visible
    float basev = s_init + (sc - tot);       // exclusive-within-wave + SOC_init
    #pragma unroll
    for (int w = 0; w < 3; ++w)
        if (w < wave) basev += s_wtot[w];
    s_base[tid] = basev;
    __syncthreads();                         // B3: bases visible

    // ---- Phase 4: add segment base, coalesced vector stores ----
    const int nvec = T / 4;
    if (!BF16) {
        float4* out4 = (float4*)outv + (size_t)b * nvec;
        for (int p = 0; p < nvec / BLOCK; ++p) {
            const int vi = p * BLOCK + tid;
            const int t0 = vi * 4;           // t0..t0+3 in same segment (L>=32)
            const float bb = s_base[t0 / L];
            float4 o;
            o.x = bb + s_g[t0     + ((t0    ) >> 5)];
            o.y = bb + s_g[t0 + 1 + ((t0 + 1) >> 5)];
            o.z = bb + s_g[t0 + 2 + ((t0 + 2) >> 5)];
            o.w = bb + s_g[t0 + 3 + ((t0 + 3) >> 5)];
            out4[vi] = o;
        }
    } else {
        ushort4* out4 = (ushort4*)outv + (size_t)b * nvec;
        for (int p = 0; p < nvec / BLOCK; ++p) {
            const int vi = p * BLOCK + tid;
            const int t0 = vi * 4;
            const float bb = s_base[t0 / L];
            ushort4 o;
            o.x = f2bf(bb + s_g[t0     + ((t0    ) >> 5)]);
            o.y = f2bf(bb + s_g[t0 + 1 + ((t0 + 1) >> 5)]);
            o.z = f2bf(bb + s_g[t0 + 2 + ((t0 + 2) >> 5)]);
            o.w = f2bf(bb + s_g[t0 + 3 + ((t0 + 3) >> 5)]);
            out4[vi] = o;
        }
    }
}

__global__ __launch_bounds__(BLOCK) void socnet_kernel(
    const void* __restrict__ X, const void* __restrict__ SC,
    const void* __restrict__ W1i, const void* __restrict__ b1i,
    const void* __restrict__ W2i, const void* __restrict__ b2i,
    const void* __restrict__ W1e, const void* __restrict__ b1e,
    const void* __restrict__ W2e, const void* __restrict__ b2e,
    void* __restrict__ out, int T)
{
    // dtype detection from SC (uniform [0.5,1.5]); resolved f32 in round 2,
    // kept for robustness (wave-uniform branch, negligible cost)
    const unsigned int* scw = (const unsigned int*)SC;
    const float l0 = bf2f(scw[0] & 0xFFFFu), l1 = bf2f(scw[1] & 0xFFFFu);
    const float l2 = bf2f(scw[2] & 0xFFFFu), l3 = bf2f(scw[3] & 0xFFFFu);
    const bool isbf =
        (l0 >= 0.45f && l0 <= 1.55f) && (l1 >= 0.45f && l1 <= 1.55f) &&
        (l2 >= 0.45f && l2 <= 1.55f) && (l3 >= 0.45f && l3 <= 1.55f);

    if (isbf) run_scan<true >(X, SC, W1i, b1i, W2i, b2i, W1e, b1e, W2e, b2e, out, T);
    else      run_scan<false>(X, SC, W1i, b1i, W2i, b2i, W1e, b1e, W2e, b2e, out, T);
}

extern "C" void kernel_launch(void* const* d_in, const int* in_sizes, int n_in,
                              void* d_out, int out_size, void* d_ws, size_t ws_size,
                              hipStream_t stream) {
    const int B = in_sizes[1] / 4;        // 1024
    const int T = in_sizes[0] / (B * 4);  // 8192

    socnet_kernel<<<dim3(B), dim3(BLOCK), 0, stream>>>(
        d_in[0], d_in[1], d_in[2], d_in[3], d_in[4], d_in[5],
        d_in[6], d_in[7], d_in[8], d_in[9], d_out, T);
}

// Round 4
// 219.137 us; speedup vs baseline: 1.3156x; 1.3156x over previous
//
#include <hip/hip_runtime.h>
#include <type_traits>

// SOC scan:  SOC[b,t] = SOC_init(b) + sum_{k<=t} g[k],  g[0]=0,
//   g[t]  = (ts[t]-ts[t-1]) * f[t-1]
//   f[t]  = (c1 + c2*softplus(I*w1e0 + Te*w1e1 + b1e)) * I[t]
//   c1 = coef*(1+b2e), c2 = coef*w2e, coef = eta0/(3600*Q)
//
// R4 structure (fixes R3 post-mortem):
//  - ONE LDS allocation at kernel scope (R3 doubled it via template instantiation
//    -> 70 KB -> 2 blocks/CU).
//  - Phase 1: wave owns contiguous span T/4; thread owns contiguous quad.
//    Predecessor of elems 1..3 is in-register; elem 0 via one shfl_up; iteration
//    carry via lane-63 broadcast shfl. NO per-iteration masked reload (R3's big
//    VALU sink).
//  - softplus via hardware v_exp/v_log (__expf/__logf); inputs |x| << 88.
//  - LDS float4 everywhere, segment stride 9 float4s (36 floats) so phase-2
//    reads sit at the b128 8-bank-group floor (no true conflicts).
//  - __launch_bounds__(256,4): 4 blocks/CU (LDS ~38 KB), VGPR capped 128.

static __device__ __forceinline__ float bf2f(unsigned int u) {
    union { unsigned int i; float f; } v;
    v.i = u << 16;
    return v.f;
}
static __device__ __forceinline__ unsigned short f2bf(float f) {
    union { unsigned int i; float f; } v;
    v.f = f;
    unsigned int x = v.i;
    return (unsigned short)((x + 0x7fffu + ((x >> 16) & 1u)) >> 16);  // RNE
}
static __device__ __forceinline__ float sp_fast(float x) {
    return __logf(1.f + __expf(x));   // v_exp_f32 / v_log_f32
}

struct F4 { float ts, I, Te, U; };
static __device__ __forceinline__ F4 dec(ushort4 x) {
    return {bf2f(x.x), bf2f(x.y), bf2f(x.z), bf2f(x.w)};
}
static __device__ __forceinline__ F4 dec(float4 x) {
    return {x.x, x.y, x.z, x.w};
}

template <bool BF16>
static __device__ __forceinline__ float ld(const void* p, int i) {
    return BF16 ? bf2f(((const unsigned short*)p)[i]) : ((const float*)p)[i];
}

constexpr int BLOCK = 256;
constexpr int MAXT  = 8192;
constexpr int SGF   = (MAXT / 32) * 36;   // skewed float count = 9216

template <bool BF16>
static __device__ void run_scan(
    const void* __restrict__ Xv, const void* __restrict__ SCv,
    const void* __restrict__ W1i, const void* __restrict__ b1i,
    const void* __restrict__ W2i, const void* __restrict__ b2i,
    const void* __restrict__ W1e, const void* __restrict__ b1e,
    const void* __restrict__ W2e, const void* __restrict__ b2e,
    void* __restrict__ outv, int T,
    float* s_g, float* s_base, float* s_wtot, float* s_init)
{
    using XVec = typename std::conditional<BF16, ushort4, float4>::type;

    const int b    = blockIdx.x;
    const int tid  = threadIdx.x;
    const int lane = tid & 63;
    const int wave = tid >> 6;
    const int span = T / 4;          // elements per wave
    const int niter = T / 1024;      // quad-iterations per wave (=8)

    const float Q    = ld<BF16>(SCv, b * 4 + 0);
    const float eta0 = ld<BF16>(SCv, b * 4 + 1);
    const float R    = ld<BF16>(SCv, b * 4 + 2);
    const float S3   = ld<BF16>(SCv, b * 4 + 3);
    const float w1e0 = ld<BF16>(W1e, 0);
    const float w1e1 = ld<BF16>(W1e, 1);
    const float vb1e = ld<BF16>(b1e, 0);
    const float coef = eta0 / (3600.f * Q);
    const float c2   = coef * ld<BF16>(W2e, 0);
    const float c1   = coef * (1.f + ld<BF16>(b2e, 0));

    const XVec* Xrow = (const XVec*)Xv + (size_t)b * T;
    float4* sg4 = (float4*)s_g;

    // wave-start carry: predecessor of element wave*span (broadcast load, once)
    float ts_c = 0.f, f_c = 0.f;
    if (wave > 0) {
        const F4 vp = dec(Xrow[wave * span - 1]);
        const float hp = sp_fast(fmaf(vp.I, w1e0, fmaf(vp.Te, w1e1, vb1e)));
        f_c  = fmaf(c2, hp, c1) * vp.I;
        ts_c = vp.ts;
    } else {
        // SOC_init head: all wave-0 lanes compute (no divergence), lane 0 writes
        const F4 v0 = dec(Xrow[0]);
        const float pre = fmaf(v0.I, ld<BF16>(W1i, 0),
                          fmaf(v0.Te, ld<BF16>(W1i, 1),
                          fmaf(v0.U, ld<BF16>(W1i, 2),
                          fmaf(R, ld<BF16>(W1i, 3), ld<BF16>(b1i, 0)))));
        const float h0 = sp_fast(pre);
        const float init = S3 * (1.f + fmaf(h0, ld<BF16>(W2i, 0), ld<BF16>(b2i, 0)));
        if (lane == 0) *s_init = init;
    }

    // ---- Phase 1: compute g, store quads to skewed LDS (no barriers) ----
    int t0 = wave * span + lane * 4;
    XVec x0 = Xrow[t0], x1 = Xrow[t0 + 1], x2 = Xrow[t0 + 2], x3 = Xrow[t0 + 3];
    for (int i = 0; i < niter; ++i) {
        XVec n0 = x0, n1 = x1, n2 = x2, n3 = x3;
        const int tn = t0 + 256;
        if (i + 1 < niter) {                 // prefetch next iteration
            n0 = Xrow[tn]; n1 = Xrow[tn + 1]; n2 = Xrow[tn + 2]; n3 = Xrow[tn + 3];
        }
        const F4 v0 = dec(x0), v1 = dec(x1), v2 = dec(x2), v3 = dec(x3);
        const float f0 = fmaf(c2, sp_fast(fmaf(v0.I, w1e0, fmaf(v0.Te, w1e1, vb1e))), c1) * v0.I;
        const float f1 = fmaf(c2, sp_fast(fmaf(v1.I, w1e0, fmaf(v1.Te, w1e1, vb1e))), c1) * v1.I;
        const float f2 = fmaf(c2, sp_fast(fmaf(v2.I, w1e0, fmaf(v2.Te, w1e1, vb1e))), c1) * v2.I;
        const float f3 = fmaf(c2, sp_fast(fmaf(v3.I, w1e0, fmaf(v3.Te, w1e1, vb1e))), c1) * v3.I;

        const float sp_ts = __shfl_up(v3.ts, 1, 64);
        const float sp_f  = __shfl_up(f3, 1, 64);
        const float pts = (lane == 0) ? ts_c : sp_ts;
        const float pf  = (lane == 0) ? f_c  : sp_f;

        float4 g;
        g.x = (t0 == 0) ? 0.f : (v0.ts - pts) * pf;
        g.y = (v1.ts - v0.ts) * f0;
        g.z = (v2.ts - v1.ts) * f1;
        g.w = (v3.ts - v2.ts) * f2;

        const int q = t0 >> 2;               // quad index
        sg4[(q >> 3) * 9 + (q & 7)] = g;

        ts_c = __shfl(v3.ts, 63, 64);        // carry for next iteration
        f_c  = __shfl(f3, 63, 64);
        t0 = tn; x0 = n0; x1 = n1; x2 = n2; x3 = n3;
    }
    __syncthreads();                         // B1: s_g + s_init complete

    // ---- Phase 2: per-thread segment scan (32 elems = 8 float4, stride 9) ----
    float run = 0.f;
    float4* segp = sg4 + tid * 9;
    #pragma unroll
    for (int j = 0; j < 8; ++j) {
        float4 v = segp[j];
        v.x += run; v.y += v.x; v.z += v.y; v.w += v.z;
        run = v.w;
        segp[j] = v;
    }

    // ---- Phase 3: block scan of segment totals ----
    const float tot = run;
    float sc = run;
    #pragma unroll
    for (int d = 1; d < 64; d <<= 1) {
        const float u = __shfl_up(sc, d, 64);
        if (lane >= d) sc += u;
    }
    if (lane == 63) s_wtot[wave] = sc;
    __syncthreads();                         // B2: wave totals + ph2 writes
    float basev = *s_init + (sc - tot);
    #pragma unroll
    for (int w = 0; w < 3; ++w)
        if (w < wave) basev += s_wtot[w];
    s_base[tid] = basev;
    __syncthreads();                         // B3: bases visible

    // ---- Phase 4: add segment base, coalesced vector stores ----
    const int npass = T / (4 * BLOCK);       // 8
    if (!BF16) {
        float4* out4 = (float4*)outv + (size_t)b * (T / 4);
        for (int p = 0; p < npass; ++p) {
            const int vi = p * BLOCK + tid;
            const float4 v = sg4[(vi >> 3) * 9 + (vi & 7)];
            const float bb = s_base[vi >> 3];
            out4[vi] = make_float4(v.x + bb, v.y + bb, v.z + bb, v.w + bb);
        }
    } else {
        ushort4* out4 = (ushort4*)outv + (size_t)b * (T / 4);
        for (int p = 0; p < npass; ++p) {
            const int vi = p * BLOCK + tid;
            const float4 v = sg4[(vi >> 3) * 9 + (vi & 7)];
            const float bb = s_base[vi >> 3];
            ushort4 o;
            o.x = f2bf(v.x + bb); o.y = f2bf(v.y + bb);
            o.z = f2bf(v.z + bb); o.w = f2bf(v.w + bb);
            out4[vi] = o;
        }
    }
}

__global__ __launch_bounds__(BLOCK, 4) void socnet_kernel(
    const void* __restrict__ X, const void* __restrict__ SC,
    const void* __restrict__ W1i, const void* __restrict__ b1i,
    const void* __restrict__ W2i, const void* __restrict__ b2i,
    const void* __restrict__ W1e, const void* __restrict__ b1e,
    const void* __restrict__ W2e, const void* __restrict__ b2e,
    void* __restrict__ out, int T)
{
    // single LDS allocation shared by both dtype paths (R3 bug: per-template
    // static __shared__ doubled LDS to 70 KB)
    __shared__ float s_g[SGF];
    __shared__ float s_base[BLOCK];
    __shared__ float s_wtot[4];
    __shared__ float s_init;

    // dtype detection from SC (uniform [0.5,1.5]); resolved f32 in round 2
    const unsigned int* scw = (const unsigned int*)SC;
    const float l0 = bf2f(scw[0] & 0xFFFFu), l1 = bf2f(scw[1] & 0xFFFFu);
    const float l2 = bf2f(scw[2] & 0xFFFFu), l3 = bf2f(scw[3] & 0xFFFFu);
    const bool isbf =
        (l0 >= 0.45f && l0 <= 1.55f) && (l1 >= 0.45f && l1 <= 1.55f) &&
        (l2 >= 0.45f && l2 <= 1.55f) && (l3 >= 0.45f && l3 <= 1.55f);

    if (isbf) run_scan<true >(X, SC, W1i, b1i, W2i, b2i, W1e, b1e, W2e, b2e,
                              out, T, s_g, s_base, s_wtot, &s_init);
    else      run_scan<false>(X, SC, W1i, b1i, W2i, b2i, W1e, b1e, W2e, b2e,
                              out, T, s_g, s_base, s_wtot, &s_init);
}

extern "C" void kernel_launch(void* const* d_in, const int* in_sizes, int n_in,
                              void* d_out, int out_size, void* d_ws, size_t ws_size,
                              hipStream_t stream) {
    const int B = in_sizes[1] / 4;        // 1024
    const int T = in_sizes[0] / (B * 4);  // 8192

    socnet_kernel<<<dim3(B), dim3(BLOCK), 0, stream>>>(
        d_in[0], d_in[1], d_in[2], d_in[3], d_in[4], d_in[5],
        d_in[6], d_in[7], d_in[8], d_in[9], d_out, T);
}